// Round 2
// baseline (816.420 us; speedup 1.0000x reference)
//
#include <hip/hip_runtime.h>

#define BB 64
#define NN 1024
#define CC 512
#define MM 16
#define SCALE 0.04419417382415922f  // 1/sqrt(512)

__device__ __forceinline__ float dot4(float4 a, float4 b) {
  return a.x*b.x + a.y*b.y + a.z*b.z + a.w*b.w;
}

// ---------------------------------------------------------------------------
// K1: P[b,m,c] = mean over 64 tokens of x.  grid 1024 (b*16+m), block 128.
__global__ void k_pool(const float* __restrict__ x, float* __restrict__ P) {
  int blk = blockIdx.x;       // b*16+m
  int t = threadIdx.x;        // 0..127 -> float4 column
  const float4* base = (const float4*)(x + (size_t)blk * 64 * CC);
  float4 a = {0.f,0.f,0.f,0.f};
  #pragma unroll 8
  for (int i = 0; i < 64; ++i) {
    float4 v = base[i*128 + t];
    a.x += v.x; a.y += v.y; a.z += v.z; a.w += v.w;
  }
  const float inv = 1.0f/64.0f;
  float4 r = {a.x*inv, a.y*inv, a.z*inv, a.w*inv};
  ((float4*)P)[(size_t)blk*128 + t] = r;
}

// ---------------------------------------------------------------------------
// Generic small Linear: Out[r,d] = sum_c In[r,c]*W[d,c] + bias[d]
// R=1024 rows, 512 out, K=512. grid dim3(16,32), block 256, 2x2 micro-tile.
__global__ void k_gemm_nt(const float* __restrict__ In, const float* __restrict__ W,
                          const float* __restrict__ bias, float* __restrict__ Out) {
  int t = threadIdx.x;
  int tx = t & 15, ty = t >> 4;
  int r0 = blockIdx.y*32 + ty*2;
  int d0 = blockIdx.x*32 + tx*2;
  const float4* In4 = (const float4*)In;
  const float4* W4  = (const float4*)W;
  float acc00=0.f, acc01=0.f, acc10=0.f, acc11=0.f;
  for (int c4 = 0; c4 < 128; ++c4) {
    float4 a0 = In4[(size_t)r0*128 + c4];
    float4 a1 = In4[(size_t)(r0+1)*128 + c4];
    float4 w0 = W4[(size_t)d0*128 + c4];
    float4 w1 = W4[(size_t)(d0+1)*128 + c4];
    acc00 += dot4(a0,w0); acc01 += dot4(a0,w1);
    acc10 += dot4(a1,w0); acc11 += dot4(a1,w1);
  }
  float b0 = bias[d0], b1 = bias[d0+1];
  float2 o0 = {acc00+b0, acc01+b1};
  float2 o1 = {acc10+b0, acc11+b1};
  *(float2*)(Out + (size_t)r0*CC + d0) = o0;
  *(float2*)(Out + (size_t)(r0+1)*CC + d0) = o1;
}

// ---------------------------------------------------------------------------
// abq[bm] = A[bm,:].bq ; abk[bm] = A[bm,:].bk.  grid 1024, block 64.
__global__ void k_abqk(const float* __restrict__ A, const float* __restrict__ bq,
                       const float* __restrict__ bk, float* __restrict__ abq,
                       float* __restrict__ abk) {
  int bm = blockIdx.x, t = threadIdx.x;
  float sq = 0.f, sk = 0.f;
  for (int d = t; d < CC; d += 64) {
    float a = A[(size_t)bm*CC + d];
    sq += a*bq[d]; sk += a*bk[d];
  }
  #pragma unroll
  for (int off = 32; off >= 1; off >>= 1) {
    sq += __shfl_xor(sq, off);
    sk += __shfl_xor(sk, off);
  }
  if (t == 0) { abq[bm] = sq; abk[bm] = sk; }
}

// ---------------------------------------------------------------------------
// Aq[r,c] = sum_d A[r,d]*Wq[d,c];  Ak[r,c] = sum_d A[r,d]*Wk[d,c]
// grid dim3(16,32), block 256, 2x2 micro-tile, outer-product along K=d.
__global__ void k_gemm_nn2(const float* __restrict__ A, const float* __restrict__ Wq,
                           const float* __restrict__ Wk, float* __restrict__ Aq,
                           float* __restrict__ Ak) {
  int t = threadIdx.x;
  int tx = t & 15, ty = t >> 4;
  int r0 = blockIdx.y*32 + ty*2;
  int c0 = blockIdx.x*32 + tx*2;
  float q00=0.f,q01=0.f,q10=0.f,q11=0.f;
  float k00=0.f,k01=0.f,k10=0.f,k11=0.f;
  #pragma unroll 4
  for (int d = 0; d < CC; ++d) {
    float a0 = A[(size_t)r0*CC + d];
    float a1 = A[(size_t)(r0+1)*CC + d];
    float2 wq = *(const float2*)(Wq + (size_t)d*CC + c0);
    float2 wk = *(const float2*)(Wk + (size_t)d*CC + c0);
    q00 += a0*wq.x; q01 += a0*wq.y; q10 += a1*wq.x; q11 += a1*wq.y;
    k00 += a0*wk.x; k01 += a0*wk.y; k10 += a1*wk.x; k11 += a1*wk.y;
  }
  float2 v;
  v.x=q00; v.y=q01; *(float2*)(Aq + (size_t)r0*CC + c0) = v;
  v.x=q10; v.y=q11; *(float2*)(Aq + (size_t)(r0+1)*CC + c0) = v;
  v.x=k00; v.y=k01; *(float2*)(Ak + (size_t)r0*CC + c0) = v;
  v.x=k10; v.y=k11; *(float2*)(Ak + (size_t)(r0+1)*CC + c0) = v;
}

// ---------------------------------------------------------------------------
// Stage-2 logits: L[b,m,n] = SCALE*(x[b,n].Ak[b,m] + abk[b,m])
// grid dim3(8,64), block 128 (one token per thread).
__global__ void k_logits(const float* __restrict__ x, const float* __restrict__ Ak,
                         const float* __restrict__ abk, float* __restrict__ L) {
  __shared__ float4 Aks[MM*128];
  __shared__ float abks[MM];
  int b = blockIdx.y, t = threadIdx.x;
  const float4* Ak4 = (const float4*)(Ak + (size_t)b*MM*CC);
  for (int i = t; i < MM*128; i += 128) Aks[i] = Ak4[i];
  if (t < MM) abks[t] = abk[b*MM + t];
  __syncthreads();
  int n = blockIdx.x*128 + t;
  const float4* xr = (const float4*)(x + ((size_t)b*NN + n)*CC);
  float acc[MM];
  #pragma unroll
  for (int m = 0; m < MM; ++m) acc[m] = 0.f;
  for (int c4 = 0; c4 < 128; ++c4) {
    float4 xv = xr[c4];
    #pragma unroll
    for (int m = 0; m < MM; ++m) acc[m] += dot4(xv, Aks[m*128 + c4]);
  }
  #pragma unroll
  for (int m = 0; m < MM; ++m)
    L[((size_t)b*MM + m)*NN + n] = SCALE*(acc[m] + abks[m]);
}

// ---------------------------------------------------------------------------
// Row softmax over N=1024, in place. grid 1024 (b*16+m), block 256.
__global__ void k_softmax(float* __restrict__ Lbuf) {
  __shared__ float red[8];
  int row = blockIdx.x, t = threadIdx.x;
  float* Lr = Lbuf + (size_t)row*NN;
  float v[4];
  #pragma unroll
  for (int i = 0; i < 4; ++i) v[i] = Lr[i*256 + t];
  float mx = fmaxf(fmaxf(v[0],v[1]), fmaxf(v[2],v[3]));
  #pragma unroll
  for (int off = 32; off >= 1; off >>= 1) mx = fmaxf(mx, __shfl_xor(mx, off));
  int wid = t >> 6;
  if ((t & 63) == 0) red[wid] = mx;
  __syncthreads();
  mx = fmaxf(fmaxf(red[0],red[1]), fmaxf(red[2],red[3]));
  float e[4], s = 0.f;
  #pragma unroll
  for (int i = 0; i < 4; ++i) { e[i] = expf(v[i]-mx); s += e[i]; }
  #pragma unroll
  for (int off = 32; off >= 1; off >>= 1) s += __shfl_xor(s, off);
  if ((t & 63) == 0) red[4+wid] = s;
  __syncthreads();
  s = red[4]+red[5]+red[6]+red[7];
  float inv = 1.0f/s;
  #pragma unroll
  for (int i = 0; i < 4; ++i) Lr[i*256 + t] = e[i]*inv;
}

// ---------------------------------------------------------------------------
// S[b,m,c] += sum_n p[b,m,n]*x[b,n,c], n-chunked with fp32 atomics.
// grid dim3(4,64), block 256.
__global__ void k_sacc(const float* __restrict__ x, const float* __restrict__ Pm,
                       float* __restrict__ S) {
  __shared__ float Ps[MM*256];
  int b = blockIdx.y, ns = blockIdx.x, t = threadIdx.x;
  for (int i = t; i < MM*256; i += 256) {
    int m = i >> 8, nl = i & 255;
    Ps[i] = Pm[((size_t)b*MM + m)*NN + ns*256 + nl];
  }
  __syncthreads();
  int c0 = t, c1 = t + 256;
  float acc0[MM], acc1[MM];
  #pragma unroll
  for (int m = 0; m < MM; ++m) { acc0[m] = 0.f; acc1[m] = 0.f; }
  const float* xb = x + ((size_t)b*NN + ns*256)*CC;
  for (int nl = 0; nl < 256; ++nl) {
    float x0 = xb[(size_t)nl*CC + c0];
    float x1 = xb[(size_t)nl*CC + c1];
    #pragma unroll
    for (int m = 0; m < MM; ++m) {
      float p = Ps[m*256 + nl];
      acc0[m] += p*x0; acc1[m] += p*x1;
    }
  }
  #pragma unroll
  for (int m = 0; m < MM; ++m) {
    atomicAdd(&S[((size_t)b*MM + m)*CC + c0], acc0[m]);
    atomicAdd(&S[((size_t)b*MM + m)*CC + c1], acc1[m]);
  }
}

// ---------------------------------------------------------------------------
// Final: per token softmax over 16 agent logits, combine G rows, write out.
// grid dim3(8,64), block 128.
__global__ void k_final(const float* __restrict__ x, const float* __restrict__ Aq,
                        const float* __restrict__ abq, const float* __restrict__ G,
                        float* __restrict__ out) {
  __shared__ float4 Aqs[MM*128];
  __shared__ float abqs[MM];
  __shared__ float ps[128*17];
  int b = blockIdx.y, t = threadIdx.x;
  const float4* Aq4 = (const float4*)(Aq + (size_t)b*MM*CC);
  for (int i = t; i < MM*128; i += 128) Aqs[i] = Aq4[i];
  if (t < MM) abqs[t] = abq[b*MM + t];
  __syncthreads();
  int n = blockIdx.x*128 + t;
  const float4* xr = (const float4*)(x + ((size_t)b*NN + n)*CC);
  float acc[MM];
  #pragma unroll
  for (int m = 0; m < MM; ++m) acc[m] = 0.f;
  for (int c4 = 0; c4 < 128; ++c4) {
    float4 xv = xr[c4];
    #pragma unroll
    for (int m = 0; m < MM; ++m) acc[m] += dot4(xv, Aqs[m*128 + c4]);
  }
  float mx = -1e30f;
  #pragma unroll
  for (int m = 0; m < MM; ++m) {
    acc[m] = SCALE*(acc[m] + abqs[m]);
    mx = fmaxf(mx, acc[m]);
  }
  float s = 0.f;
  #pragma unroll
  for (int m = 0; m < MM; ++m) { acc[m] = expf(acc[m]-mx); s += acc[m]; }
  float inv = 1.0f/s;
  #pragma unroll
  for (int m = 0; m < MM; ++m) ps[t*17 + m] = acc[m]*inv;
  // G rows for this thread's float4 column, kept in registers
  float4 g[MM];
  const float4* G4 = (const float4*)(G + (size_t)b*MM*CC);
  #pragma unroll
  for (int m = 0; m < MM; ++m) g[m] = G4[m*128 + t];
  __syncthreads();
  float4* out4 = (float4*)(out + ((size_t)b*NN + blockIdx.x*128)*CC);
  for (int sx = 0; sx < 128; ++sx) {
    float4 o = {0.f,0.f,0.f,0.f};
    #pragma unroll
    for (int m = 0; m < MM; ++m) {
      float p = ps[sx*17 + m];
      o.x += p*g[m].x; o.y += p*g[m].y; o.z += p*g[m].z; o.w += p*g[m].w;
    }
    out4[(size_t)sx*128 + t] = o;
  }
}

// ---------------------------------------------------------------------------
extern "C" void kernel_launch(void* const* d_in, const int* in_sizes, int n_in,
                              void* d_out, int out_size, void* d_ws, size_t ws_size,
                              hipStream_t stream) {
  (void)in_sizes; (void)n_in; (void)out_size; (void)ws_size;
  const float* x  = (const float*)d_in[0];
  const float* Wq = (const float*)d_in[1];
  const float* bq = (const float*)d_in[2];
  const float* Wk = (const float*)d_in[3];
  const float* bk = (const float*)d_in[4];
  const float* Wv = (const float*)d_in[5];
  const float* bv = (const float*)d_in[6];
  const float* Wo = (const float*)d_in[7];
  const float* bo = (const float*)d_in[8];
  float* out = (float*)d_out;

  float* ws  = (float*)d_ws;
  float* P   = ws;                    // 1024*512
  float* A   = P  + 1024*512;         // 1024*512
  float* Aq  = A  + 1024*512;         // 1024*512
  float* Ak  = Aq + 1024*512;         // 1024*512
  float* abq = Ak + 1024*512;         // 1024
  float* abk = abq + 1024;            // 1024
  float* Lb  = abk + 1024;            // 1024*1024 (logits -> softmax in place)
  float* S   = Lb + 1024*1024;        // 1024*512
  float* AF  = S  + 1024*512;         // 1024*512
  float* G   = AF + 1024*512;         // 1024*512

  hipMemsetAsync(S, 0, (size_t)1024*512*sizeof(float), stream);
  k_pool<<<1024, 128, 0, stream>>>(x, P);
  k_gemm_nt<<<dim3(16,32), 256, 0, stream>>>(P, Wq, bq, A);
  k_abqk<<<1024, 64, 0, stream>>>(A, bq, bk, abq, abk);
  k_gemm_nn2<<<dim3(16,32), 256, 0, stream>>>(A, Wq, Wk, Aq, Ak);
  k_logits<<<dim3(8,64), 128, 0, stream>>>(x, Ak, abk, Lb);
  k_softmax<<<1024, 256, 0, stream>>>(Lb);
  k_sacc<<<dim3(4,64), 256, 0, stream>>>(x, Lb, S);
  k_gemm_nt<<<dim3(16,32), 256, 0, stream>>>(S, Wv, bv, AF);
  k_gemm_nt<<<dim3(16,32), 256, 0, stream>>>(AF, Wo, bo, G);
  k_final<<<dim3(8,64), 128, 0, stream>>>(x, Aq, abq, G, out);
}